// Round 2
// baseline (359.545 us; speedup 1.0000x reference)
//
#include <hip/hip_runtime.h>
#include <hip/hip_bf16.h>
#include <math.h>

// qkv_attn: x[8,16384,256] fp32. Linear attention with per-head(16) LN on k,v.
// Strategy: kv = LN(k)^T LN(v) / HW accumulated globally (K1, MFMA + atomics),
// then fold kv into Wq => Wq_eff[b] (K2), then fused double-GEMM epilogue (K3).
// All GEMMs in bf16 MFMA (16x16x32), fp32 accumulate; residuals added in fp32.

#define HWN 16384
#define EPSF 1e-5f

typedef __bf16 bf16x8 __attribute__((ext_vector_type(8)));
typedef __bf16 bf16x4 __attribute__((ext_vector_type(4)));
typedef float  f32x4  __attribute__((ext_vector_type(4)));

// ---------------- K0: weight prep (fp32 -> bf16, de-interleave k/v rows), zero kv accum ----
__global__ void k0_prep(const float* __restrict__ Wqkv, const float* __restrict__ Wproj,
                        __bf16* __restrict__ Wkv, __bf16* __restrict__ Wp,
                        float* __restrict__ kv) {
  int idx = blockIdx.x * 256 + threadIdx.x;   // grid 512*256 = 131072
  if (idx < 32768) kv[idx] = 0.f;             // kv accumulator [8][16][16][16]
  {
    // Wkv row r: r<256 -> k-head rows (W_qkv row h*48+16+d), r>=256 -> v rows (h*48+32+d)
    int r = idx >> 8, c = idx & 255;
    int half = r >> 8;          // 0:k 1:v
    int rr = r & 255;
    int h = rr >> 4, d = rr & 15;
    Wkv[idx] = (__bf16)Wqkv[(h*48 + 16 + half*16 + d)*256 + c];
  }
  if (idx < 65536) Wp[idx] = (__bf16)Wproj[idx];
}

// ---------------- K1: k,v GEMM + LN + kv outer-product accumulation ----------------
// block: 512 thr (8 waves), 64 rows. wave w computes all 64 rows x cols [w*64, w*64+64)
// of the 512-wide k|v output. LN per 16-col head segment via shfl within 16-lane groups.
__launch_bounds__(512)
__global__ void k1_kv(const float* __restrict__ x, const __bf16* __restrict__ Wkv,
                      const float* __restrict__ bqkv,
                      const float* __restrict__ klnw, const float* __restrict__ klnb,
                      const float* __restrict__ vlnw, const float* __restrict__ vlnb,
                      float* __restrict__ kvout) {
  // smem reused: phase A = x tile [64][264] bf16 (33.8KB); phase B = kT/vT [32][16][72] (73.7KB)
  __shared__ __align__(16) char smem[73728];
  __bf16 (*xs)[264]     = reinterpret_cast<__bf16(*)[264]>(smem);
  __bf16 (*tT)[16][72]  = reinterpret_cast<__bf16(*)[16][72]>(smem); // [isv*16+h][d_or_e][r]

  const int tid = threadIdx.x;
  const long browg = (long)blockIdx.x * 64;
  const int b = (int)(browg >> 14);

  // stage x tile -> bf16 LDS
  #pragma unroll
  for (int i = 0; i < 8; ++i) {
    int idx = tid + i*512;
    int r = idx >> 6, c4 = (idx & 63) << 2;
    f32x4 v = *reinterpret_cast<const f32x4*>(x + (browg + r)*256 + c4);
    bf16x4 pk; pk[0]=(__bf16)v[0]; pk[1]=(__bf16)v[1]; pk[2]=(__bf16)v[2]; pk[3]=(__bf16)v[3];
    *reinterpret_cast<bf16x4*>(&xs[r][c4]) = pk;
  }
  __syncthreads();

  const int w = tid >> 6, l = tid & 63, lr = l & 15, g = l >> 4;

  f32x4 acc[4][4];
  for (int i=0;i<4;i++)
    for (int j=0;j<4;j++) {
      acc[i][j][0]=0.f; acc[i][j][1]=0.f; acc[i][j][2]=0.f; acc[i][j][3]=0.f;
    }

  #pragma unroll
  for (int kc = 0; kc < 8; ++kc) {
    const int kb = kc*32 + g*8;
    bf16x8 afr[4];
    #pragma unroll
    for (int rb=0;rb<4;rb++)
      afr[rb] = *reinterpret_cast<const bf16x8*>(&xs[rb*16+lr][kb]);
    #pragma unroll
    for (int cb=0;cb<4;cb++) {
      const int col = w*64 + cb*16 + lr;
      bf16x8 bfr = *reinterpret_cast<const bf16x8*>(Wkv + (size_t)col*256 + kb);
      #pragma unroll
      for (int rb=0;rb<4;rb++)
        acc[rb][cb] = __builtin_amdgcn_mfma_f32_16x16x32_bf16(afr[rb], bfr, acc[rb][cb], 0,0,0);
    }
  }
  __syncthreads();   // done with xs; smem becomes tT

  // LN (per row, over the 16 cols of a head segment = one col-block) + transposed store
  #pragma unroll
  for (int cb=0;cb<4;cb++) {
    const int colg = w*64 + cb*16;
    const int isv = colg >> 8;
    const int h = (colg & 255) >> 4;
    const float bias = bqkv[h*48 + 16 + isv*16 + lr];
    const float lw = (isv ? vlnw : klnw)[h*16 + lr];
    const float lb = (isv ? vlnb : klnb)[h*16 + lr];
    #pragma unroll
    for (int rb=0;rb<4;rb++) {
      f32x4 a = acc[rb][cb];
      bf16x4 pk;
      #pragma unroll
      for (int t=0;t<4;t++) {
        float val = a[t] + bias;
        float s = val;
        s += __shfl_xor(s,1); s += __shfl_xor(s,2); s += __shfl_xor(s,4); s += __shfl_xor(s,8);
        float mean = s * 0.0625f;
        float df = val - mean;
        float q2 = df*df;
        q2 += __shfl_xor(q2,1); q2 += __shfl_xor(q2,2); q2 += __shfl_xor(q2,4); q2 += __shfl_xor(q2,8);
        float stdv = sqrtf(q2 * (1.f/15.f));              // ddof=1
        pk[t] = (__bf16)(lw * df / (stdv + EPSF) + lb);   // /(std+eps), faithful
      }
      // rows r = rb*16+g*4+{0..3} contiguous -> 8B store at tT[isv*16+h][lr][r]
      *reinterpret_cast<bf16x4*>(&tT[isv*16+h][lr][rb*16 + g*4]) = pk;
    }
  }
  __syncthreads();

  // kv_h += K'^T V' over 64 rows: 2 MFMA per head; wave w owns heads 2w, 2w+1
  #pragma unroll
  for (int hh=0; hh<2; ++hh) {
    const int h = w*2 + hh;
    f32x4 c; c[0]=0.f; c[1]=0.f; c[2]=0.f; c[3]=0.f;
    #pragma unroll
    for (int ch=0; ch<2; ++ch) {
      bf16x8 afr = *reinterpret_cast<const bf16x8*>(&tT[h][lr][ch*32 + g*8]);      // A[d][r]
      bf16x8 bfr = *reinterpret_cast<const bf16x8*>(&tT[16+h][lr][ch*32 + g*8]);   // B[r][e]
      c = __builtin_amdgcn_mfma_f32_16x16x32_bf16(afr, bfr, c, 0,0,0);
    }
    float* dst = kvout + ((b*16 + h) * 256);
    #pragma unroll
    for (int t=0;t<4;t++)
      atomicAdd(dst + (g*4+t)*16 + lr, c[t]);   // kv[b][h][d=g*4+t][e=lr]
  }
}

// ---------------- K2: Wq_eff[b][h*16+e][c] = sum_d kv[b,h,d,e]/HW * Wq[h*48+d][c] ----------
__global__ void k2_weff(const float* __restrict__ Wqkv, const float* __restrict__ bqkv,
                        const float* __restrict__ kvin,
                        __bf16* __restrict__ Wqe, float* __restrict__ beff) {
  const int b = blockIdx.x >> 4, h = blockIdx.x & 15;
  const int c = threadIdx.x;
  __shared__ float kvs[16][16]; // [d][e]
  kvs[c >> 4][c & 15] = kvin[(b*16 + h)*256 + c] * (1.f/16384.f);
  __syncthreads();
  #pragma unroll 4
  for (int e=0;e<16;e++) {
    float acc = 0.f;
    #pragma unroll
    for (int d=0; d<16; d++)
      acc += kvs[d][e] * Wqkv[(h*48 + d)*256 + c];
    Wqe[((size_t)b*256 + h*16 + e)*256 + c] = (__bf16)acc;
  }
  if (c < 16) {
    float acc = 0.f;
    #pragma unroll
    for (int d=0; d<16; d++) acc += kvs[d][c] * bqkv[h*48 + d];
    beff[b*256 + h*16 + c] = acc;
  }
}

// ---------------- K3: fused  o = x@Wq_eff^T + beff; ret = o + x; proj = ret@Wp^T + bp;
//                            y = gelu_exact(proj) + x ----------------
__launch_bounds__(512)
__global__ void k3_fused(const float* __restrict__ x, const __bf16* __restrict__ Wqe,
                         const float* __restrict__ beff, const __bf16* __restrict__ Wp,
                         const float* __restrict__ bproj, float* __restrict__ out) {
  __shared__ __align__(16) __bf16 xs[64][264];
  __shared__ __align__(16) __bf16 rs[64][264];
  const int tid = threadIdx.x;
  const long browg = (long)blockIdx.x * 64;
  const int b = (int)(browg >> 14);

  #pragma unroll
  for (int i = 0; i < 8; ++i) {
    int idx = tid + i*512;
    int r = idx >> 6, c4 = (idx & 63) << 2;
    f32x4 v = *reinterpret_cast<const f32x4*>(x + (browg + r)*256 + c4);
    bf16x4 pk; pk[0]=(__bf16)v[0]; pk[1]=(__bf16)v[1]; pk[2]=(__bf16)v[2]; pk[3]=(__bf16)v[3];
    *reinterpret_cast<bf16x4*>(&xs[r][c4]) = pk;
  }
  __syncthreads();

  const int w = tid>>6, l = tid&63, lr = l&15, g = l>>4;
  const __bf16* Bq = Wqe + (size_t)b*65536;

  f32x4 acc[4][2];
  for (int i=0;i<4;i++)
    for (int j=0;j<2;j++) {
      acc[i][j][0]=0.f; acc[i][j][1]=0.f; acc[i][j][2]=0.f; acc[i][j][3]=0.f;
    }
  #pragma unroll
  for (int kc=0;kc<8;kc++) {
    const int kb = kc*32 + g*8;
    bf16x8 afr[4];
    #pragma unroll
    for (int rb=0;rb<4;rb++)
      afr[rb] = *reinterpret_cast<const bf16x8*>(&xs[rb*16+lr][kb]);
    #pragma unroll
    for (int cb=0;cb<2;cb++) {
      const int col = w*32 + cb*16 + lr;
      bf16x8 bfr = *reinterpret_cast<const bf16x8*>(Bq + (size_t)col*256 + kb);
      #pragma unroll
      for (int rb=0;rb<4;rb++)
        acc[rb][cb] = __builtin_amdgcn_mfma_f32_16x16x32_bf16(afr[rb], bfr, acc[rb][cb], 0,0,0);
    }
  }
  // ret = o + beff + x  (bf16 into rs)
  #pragma unroll
  for (int cb=0;cb<2;cb++) {
    const int col = w*32 + cb*16 + lr;
    const float be = beff[b*256 + col];
    #pragma unroll
    for (int rb=0;rb<4;rb++) {
      #pragma unroll
      for (int t=0;t<4;t++) {
        const int r = rb*16 + g*4 + t;
        rs[r][col] = (__bf16)(acc[rb][cb][t] + be + (float)xs[r][col]);
      }
    }
  }
  __syncthreads();

  f32x4 acc2[4][2];
  for (int i=0;i<4;i++)
    for (int j=0;j<2;j++) {
      acc2[i][j][0]=0.f; acc2[i][j][1]=0.f; acc2[i][j][2]=0.f; acc2[i][j][3]=0.f;
    }
  #pragma unroll
  for (int kc=0;kc<8;kc++) {
    const int kb = kc*32 + g*8;
    bf16x8 afr[4];
    #pragma unroll
    for (int rb=0;rb<4;rb++)
      afr[rb] = *reinterpret_cast<const bf16x8*>(&rs[rb*16+lr][kb]);
    #pragma unroll
    for (int cb=0;cb<2;cb++) {
      const int col = w*32 + cb*16 + lr;
      bf16x8 bfr = *reinterpret_cast<const bf16x8*>(Wp + (size_t)col*256 + kb);
      #pragma unroll
      for (int rb=0;rb<4;rb++)
        acc2[rb][cb] = __builtin_amdgcn_mfma_f32_16x16x32_bf16(afr[rb], bfr, acc2[rb][cb], 0,0,0);
    }
  }
  // epilogue: gelu(proj + bp) + x (fp32 from global, L2-hot)
  #pragma unroll
  for (int cb=0;cb<2;cb++) {
    const int col = w*32 + cb*16 + lr;
    const float bp = bproj[col];
    #pragma unroll
    for (int rb=0;rb<4;rb++) {
      #pragma unroll
      for (int t=0;t<4;t++) {
        const int r = rb*16 + g*4 + t;
        const long gr = browg + r;
        float z = acc2[rb][cb][t] + bp;
        float ge = 0.5f*z*(1.f + erff(z*0.70710678118f));
        out[gr*256 + col] = ge + x[gr*256 + col];
      }
    }
  }
}

extern "C" void kernel_launch(void* const* d_in, const int* in_sizes, int n_in,
                              void* d_out, int out_size, void* d_ws, size_t ws_size,
                              hipStream_t stream) {
  const float* x    = (const float*)d_in[0];
  const float* Wqkv = (const float*)d_in[1];
  const float* bqkv = (const float*)d_in[2];
  const float* klnw = (const float*)d_in[3];
  const float* klnb = (const float*)d_in[4];
  const float* vlnw = (const float*)d_in[5];
  const float* vlnb = (const float*)d_in[6];
  const float* Wproj= (const float*)d_in[7];
  const float* bproj= (const float*)d_in[8];
  float* out = (float*)d_out;

  char* ws = (char*)d_ws;
  __bf16* Wkv = (__bf16*)(ws);                 // 512*256*2   = 262144
  __bf16* Wp  = (__bf16*)(ws + 262144);        // 256*256*2   = 131072
  float*  kv  = (float*) (ws + 393216);        // 32768*4     = 131072
  __bf16* Wqe = (__bf16*)(ws + 524288);        // 8*256*256*2 = 1048576
  float*  beff= (float*) (ws + 1572864);       // 8*256*4     = 8192

  k0_prep <<<512, 256, 0, stream>>>(Wqkv, Wproj, Wkv, Wp, kv);
  k1_kv   <<<2048, 512, 0, stream>>>(x, Wkv, bqkv, klnw, klnb, vlnw, vlnb, kv);
  k2_weff <<<128, 256, 0, stream>>>(Wqkv, bqkv, kv, Wqe, beff);
  k3_fused<<<2048, 512, 0, stream>>>(x, Wqe, beff, Wp, bproj, out);
}

// Round 3
// 357.621 us; speedup vs baseline: 1.0054x; 1.0054x over previous
//
#include <hip/hip_runtime.h>
#include <hip/hip_bf16.h>
#include <math.h>

// qkv_attn: x[8,16384,256] fp32. kv = LN(k)^T LN(v)/HW folded into Wq (per batch),
// K1: swapped-operand MFMA so LN head-dim is lane-local (2 shfls per reduce),
// grid-stride tiles with register kv accumulation (4x fewer atomics).
// K3: swapped-operand double GEMM -> vectorized f32x4 epilogue stores.

#define EPSF 1e-5f

typedef __bf16 bf16x8 __attribute__((ext_vector_type(8)));
typedef __bf16 bf16x4 __attribute__((ext_vector_type(4)));
typedef float  f32x4  __attribute__((ext_vector_type(4)));

// ---------------- K0: weight prep (fp32 -> bf16, de-interleave k/v rows), zero kv accum ----
__global__ void k0_prep(const float* __restrict__ Wqkv, const float* __restrict__ Wproj,
                        __bf16* __restrict__ Wkv, __bf16* __restrict__ Wp,
                        float* __restrict__ kv) {
  int idx = blockIdx.x * 256 + threadIdx.x;   // grid 512*256 = 131072
  if (idx < 32768) kv[idx] = 0.f;             // kv accumulator [8][16][16][16]
  {
    int r = idx >> 8, c = idx & 255;
    int half = r >> 8;          // 0:k 1:v
    int rr = r & 255;
    int h = rr >> 4, d = rr & 15;
    Wkv[idx] = (__bf16)Wqkv[(h*48 + 16 + half*16 + d)*256 + c];
  }
  if (idx < 65536) Wp[idx] = (__bf16)Wproj[idx];
}

// ---------------- K1: k,v GEMM (swapped operands) + lane-local LN + kv accumulation ----
// 512 blocks (2/CU, all resident), each does 4 tiles of 64 rows within one batch b.
// Wave w owns heads {2w, 2w+1}: 4 d-blocks (k and v of both heads) x 4 row-blocks.
// MFMA output D[d][r]: lane(g,lr) holds d=4g+j (j=0..3), r=lr -> LN over d is
// 3 adds + shfl_xor(16) + shfl_xor(32).
__launch_bounds__(512, 4)
__global__ void k1_kv(const float* __restrict__ x, const __bf16* __restrict__ Wkv,
                      const float* __restrict__ bqkv,
                      const float* __restrict__ klnw, const float* __restrict__ klnb,
                      const float* __restrict__ vlnw, const float* __restrict__ vlnb,
                      float* __restrict__ kvout) {
  __shared__ __align__(16) char smem[73728];
  __bf16 (*xs)[264] = reinterpret_cast<__bf16(*)[264]>(smem);   // phase A: x tile (33.8KB)

  const int tid = threadIdx.x;
  const int w = tid >> 6, l = tid & 63, lr = l & 15, g = l >> 4;
  const int b  = blockIdx.x >> 6;          // 64 blocks per batch
  const int t0 = (blockIdx.x & 63) << 2;   // 4 consecutive 64-row tiles
  // phase B: per-wave transposed k'/v' tiles [slot(4)][d(16)][r(72 pad)] bf16 = 9216B/wave
  __bf16 (*tTw)[16][72] = reinterpret_cast<__bf16(*)[16][72]>(smem + w*9216);
  const int h0 = 2*w;

  f32x4 kvacc[2];
  for (int j=0;j<4;j++) { kvacc[0][j]=0.f; kvacc[1][j]=0.f; }

  for (int t = 0; t < 4; ++t) {
    const long row0 = (long)b*16384 + (long)(t0 + t)*64;
    __syncthreads();   // previous tile's tT reads done before restaging
    #pragma unroll
    for (int i = 0; i < 8; ++i) {
      int idx = tid + i*512;
      int r = idx >> 6, c4 = (idx & 63) << 2;
      f32x4 v = *reinterpret_cast<const f32x4*>(x + (row0 + r)*256 + c4);
      bf16x4 pk; pk[0]=(__bf16)v[0]; pk[1]=(__bf16)v[1]; pk[2]=(__bf16)v[2]; pk[3]=(__bf16)v[3];
      *reinterpret_cast<bf16x4*>(&xs[r][c4]) = pk;
    }
    __syncthreads();

    f32x4 acc[4][4];   // [slot][rb]
    for (int s=0;s<4;s++)
      for (int rb=0;rb<4;rb++)
        for (int j=0;j<4;j++) acc[s][rb][j]=0.f;

    #pragma unroll
    for (int kc = 0; kc < 8; ++kc) {
      const int kb = kc*32 + g*8;
      bf16x8 af[4], bf_[4];
      #pragma unroll
      for (int s=0;s<4;s++) {
        const int wr = ((s>>1)<<8) + ((h0 + (s&1))<<4) + lr;   // Wkv row
        af[s] = *reinterpret_cast<const bf16x8*>(Wkv + (size_t)wr*256 + kb);
      }
      #pragma unroll
      for (int rb=0;rb<4;rb++)
        bf_[rb] = *reinterpret_cast<const bf16x8*>(&xs[rb*16+lr][kb]);
      #pragma unroll
      for (int s=0;s<4;s++) {
        #pragma unroll
        for (int rb=0;rb<4;rb++)
          acc[s][rb] = __builtin_amdgcn_mfma_f32_16x16x32_bf16(af[s], bf_[rb], acc[s][rb], 0,0,0);
      }
    }
    __syncthreads();   // xs dead; smem becomes tT

    // LN per (slot, row-block): lane-local over 4 regs + 2 shfls; transposed bf16 store
    #pragma unroll
    for (int s=0;s<4;s++) {
      const int h = h0 + (s&1), isv = s>>1;
      const f32x4 bb  = *reinterpret_cast<const f32x4*>(bqkv + h*48 + 16 + isv*16 + 4*g);
      const f32x4 lwv = *reinterpret_cast<const f32x4*>((isv ? vlnw : klnw) + h*16 + 4*g);
      const f32x4 lbv = *reinterpret_cast<const f32x4*>((isv ? vlnb : klnb) + h*16 + 4*g);
      #pragma unroll
      for (int rb=0;rb<4;rb++) {
        float v0 = acc[s][rb][0] + bb[0];
        float v1 = acc[s][rb][1] + bb[1];
        float v2 = acc[s][rb][2] + bb[2];
        float v3 = acc[s][rb][3] + bb[3];
        float sum = v0+v1+v2+v3;
        sum += __shfl_xor(sum, 16); sum += __shfl_xor(sum, 32);
        const float mu = sum * 0.0625f;
        const float d0=v0-mu, d1=v1-mu, d2=v2-mu, d3=v3-mu;
        float q = d0*d0 + d1*d1 + d2*d2 + d3*d3;
        q += __shfl_xor(q, 16); q += __shfl_xor(q, 32);
        const float sc = 1.f/(sqrtf(q*(1.f/15.f)) + EPSF);   // ddof=1, /(std+eps)
        const int rr = rb*16 + lr;
        tTw[s][4*g+0][rr] = (__bf16)(lwv[0]*d0*sc + lbv[0]);
        tTw[s][4*g+1][rr] = (__bf16)(lwv[1]*d1*sc + lbv[1]);
        tTw[s][4*g+2][rr] = (__bf16)(lwv[2]*d2*sc + lbv[2]);
        tTw[s][4*g+3][rr] = (__bf16)(lwv[3]*d3*sc + lbv[3]);
      }
    }
    __syncthreads();

    // kv_h += k'^T v' over this tile's 64 rows (2 heads/wave, 2 chunks of 32 rows)
    #pragma unroll
    for (int hh=0; hh<2; ++hh) {
      #pragma unroll
      for (int ch=0; ch<2; ++ch) {
        bf16x8 a  = *reinterpret_cast<const bf16x8*>(&tTw[hh  ][lr][ch*32 + g*8]);
        bf16x8 bv = *reinterpret_cast<const bf16x8*>(&tTw[2+hh][lr][ch*32 + g*8]);
        kvacc[hh] = __builtin_amdgcn_mfma_f32_16x16x32_bf16(a, bv, kvacc[hh], 0,0,0);
      }
    }
  }

  #pragma unroll
  for (int hh=0; hh<2; ++hh) {
    float* dst = kvout + ((size_t)(b*16 + h0 + hh) << 8);
    #pragma unroll
    for (int j=0;j<4;j++)
      atomicAdd(dst + (4*g+j)*16 + lr, kvacc[hh][j]);   // kv[b][h][d=4g+j][e=lr]
  }
}

// ---------------- K2: Wq_eff[b][h*16+e][c] = sum_d kv[b,h,d,e]/HW * Wq[h*48+d][c] ----------
__global__ void k2_weff(const float* __restrict__ Wqkv, const float* __restrict__ bqkv,
                        const float* __restrict__ kvin,
                        __bf16* __restrict__ Wqe, float* __restrict__ beff) {
  const int b = blockIdx.x >> 4, h = blockIdx.x & 15;
  const int c = threadIdx.x;
  __shared__ float kvs[16][16]; // [d][e]
  kvs[c >> 4][c & 15] = kvin[(b*16 + h)*256 + c] * (1.f/16384.f);
  __syncthreads();
  #pragma unroll 4
  for (int e=0;e<16;e++) {
    float acc = 0.f;
    #pragma unroll
    for (int d=0; d<16; d++)
      acc += kvs[d][e] * Wqkv[(h*48 + d)*256 + c];
    Wqe[((size_t)b*256 + h*16 + e)*256 + c] = (__bf16)acc;
  }
  if (c < 16) {
    float acc = 0.f;
    #pragma unroll
    for (int d=0; d<16; d++) acc += kvs[d][c] * bqkv[h*48 + d];
    beff[b*256 + h*16 + c] = acc;
  }
}

// ---------------- K3: fused o = x@Wq_eff^T; ret = o+beff+x; proj = ret@Wp^T; y=gelu+x ----
// Swapped operands: D[col][row] -> lane(g,lr) owns 4 consecutive cols of one row
// => bf16x4 LDS writes and f32x4 global loads/stores in the epilogue.
__launch_bounds__(512, 4)
__global__ void k3_fused(const float* __restrict__ x, const __bf16* __restrict__ Wqe,
                         const float* __restrict__ beff, const __bf16* __restrict__ Wp,
                         const float* __restrict__ bproj, float* __restrict__ out) {
  __shared__ __align__(16) __bf16 xs[64][264];
  __shared__ __align__(16) __bf16 rs[64][264];
  const int tid = threadIdx.x;
  const long browg = (long)blockIdx.x * 64;
  const int b = (int)(browg >> 14);
  const int w = tid>>6, l = tid&63, lr = l&15, g = l>>4;

  #pragma unroll
  for (int i = 0; i < 8; ++i) {
    int idx = tid + i*512;
    int r = idx >> 6, c4 = (idx & 63) << 2;
    f32x4 v = *reinterpret_cast<const f32x4*>(x + (browg + r)*256 + c4);
    bf16x4 pk; pk[0]=(__bf16)v[0]; pk[1]=(__bf16)v[1]; pk[2]=(__bf16)v[2]; pk[3]=(__bf16)v[3];
    *reinterpret_cast<bf16x4*>(&xs[r][c4]) = pk;
  }
  __syncthreads();

  const __bf16* Bq = Wqe + (size_t)b*65536;

  // GEMM1 (swapped): acc[cb][rb] -> cols w*32+cb*16+4g+j, row rb*16+lr
  f32x4 acc[2][4];
  for (int cb=0;cb<2;cb++)
    for (int rb=0;rb<4;rb++)
      for (int j=0;j<4;j++) acc[cb][rb][j]=0.f;
  #pragma unroll
  for (int kc=0;kc<8;kc++) {
    const int kb = kc*32 + g*8;
    bf16x8 af[2], bf_[4];
    #pragma unroll
    for (int cb=0;cb<2;cb++)
      af[cb] = *reinterpret_cast<const bf16x8*>(Bq + (size_t)(w*32 + cb*16 + lr)*256 + kb);
    #pragma unroll
    for (int rb=0;rb<4;rb++)
      bf_[rb] = *reinterpret_cast<const bf16x8*>(&xs[rb*16+lr][kb]);
    #pragma unroll
    for (int cb=0;cb<2;cb++) {
      #pragma unroll
      for (int rb=0;rb<4;rb++)
        acc[cb][rb] = __builtin_amdgcn_mfma_f32_16x16x32_bf16(af[cb], bf_[rb], acc[cb][rb], 0,0,0);
    }
  }

  // ret = o + beff + x -> rs (bf16x4 vector writes; rs is a separate buffer)
  #pragma unroll
  for (int cb=0;cb<2;cb++) {
    const int c0 = w*32 + cb*16 + 4*g;
    const f32x4 be = *reinterpret_cast<const f32x4*>(beff + b*256 + c0);
    #pragma unroll
    for (int rb=0;rb<4;rb++) {
      const int r = rb*16 + lr;
      bf16x4 xv = *reinterpret_cast<const bf16x4*>(&xs[r][c0]);
      bf16x4 pk;
      #pragma unroll
      for (int j=0;j<4;j++)
        pk[j] = (__bf16)(acc[cb][rb][j] + be[j] + (float)xv[j]);
      *reinterpret_cast<bf16x4*>(&rs[r][c0]) = pk;
    }
  }
  __syncthreads();

  // GEMM2 (swapped): proj cols w*32+cb*16+4g+j
  f32x4 acc2[2][4];
  for (int cb=0;cb<2;cb++)
    for (int rb=0;rb<4;rb++)
      for (int j=0;j<4;j++) acc2[cb][rb][j]=0.f;
  #pragma unroll
  for (int kc=0;kc<8;kc++) {
    const int kb = kc*32 + g*8;
    bf16x8 af[2], bf_[4];
    #pragma unroll
    for (int cb=0;cb<2;cb++)
      af[cb] = *reinterpret_cast<const bf16x8*>(Wp + (size_t)(w*32 + cb*16 + lr)*256 + kb);
    #pragma unroll
    for (int rb=0;rb<4;rb++)
      bf_[rb] = *reinterpret_cast<const bf16x8*>(&rs[rb*16+lr][kb]);
    #pragma unroll
    for (int cb=0;cb<2;cb++) {
      #pragma unroll
      for (int rb=0;rb<4;rb++)
        acc2[cb][rb] = __builtin_amdgcn_mfma_f32_16x16x32_bf16(af[cb], bf_[rb], acc2[cb][rb], 0,0,0);
    }
  }

  // epilogue: y = gelu_exact(proj + bp) + x, fully vectorized f32x4
  #pragma unroll
  for (int cb=0;cb<2;cb++) {
    const int c0 = w*32 + cb*16 + 4*g;
    const f32x4 bp4 = *reinterpret_cast<const f32x4*>(bproj + c0);
    #pragma unroll
    for (int rb=0;rb<4;rb++) {
      const long gr = browg + rb*16 + lr;
      const f32x4 xv = *reinterpret_cast<const f32x4*>(x + gr*256 + c0);
      f32x4 o;
      #pragma unroll
      for (int j=0;j<4;j++) {
        float z = acc2[cb][rb][j] + bp4[j];
        o[j] = 0.5f*z*(1.f + erff(z*0.70710678118f)) + xv[j];
      }
      *reinterpret_cast<f32x4*>(out + gr*256 + c0) = o;
    }
  }
}

extern "C" void kernel_launch(void* const* d_in, const int* in_sizes, int n_in,
                              void* d_out, int out_size, void* d_ws, size_t ws_size,
                              hipStream_t stream) {
  const float* x    = (const float*)d_in[0];
  const float* Wqkv = (const float*)d_in[1];
  const float* bqkv = (const float*)d_in[2];
  const float* klnw = (const float*)d_in[3];
  const float* klnb = (const float*)d_in[4];
  const float* vlnw = (const float*)d_in[5];
  const float* vlnb = (const float*)d_in[6];
  const float* Wproj= (const float*)d_in[7];
  const float* bproj= (const float*)d_in[8];
  float* out = (float*)d_out;

  char* ws = (char*)d_ws;
  __bf16* Wkv = (__bf16*)(ws);                 // 512*256*2   = 262144
  __bf16* Wp  = (__bf16*)(ws + 262144);        // 256*256*2   = 131072
  float*  kv  = (float*) (ws + 393216);        // 32768*4     = 131072
  __bf16* Wqe = (__bf16*)(ws + 524288);        // 8*256*256*2 = 1048576
  float*  beff= (float*) (ws + 1572864);       // 8*256*4     = 8192

  k0_prep <<<512, 256, 0, stream>>>(Wqkv, Wproj, Wkv, Wp, kv);
  k1_kv   <<<512, 512, 0, stream>>>(x, Wkv, bqkv, klnw, klnb, vlnw, vlnb, kv);
  k2_weff <<<128, 256, 0, stream>>>(Wqkv, bqkv, kv, Wqe, beff);
  k3_fused<<<2048, 512, 0, stream>>>(x, Wqe, beff, Wp, bproj, out);
}

// Round 4
// 251.455 us; speedup vs baseline: 1.4299x; 1.4222x over previous
//
#include <hip/hip_runtime.h>
#include <hip/hip_bf16.h>
#include <math.h>

// qkv_attn: x[8,16384,256] fp32. kv = LN(k)^T LN(v)/HW folded into Wq (per batch).
// R4: K1 split into K1a (k/v GEMM + LN -> transposed bf16 k',v' streamed to d_out-as-scratch)
// and K1b (streaming MFMA reduction kv = k'^T v'). Removes the spill-inducing
// launch_bounds and the 4-phase barrier chain that latency-bound the old K1.

#define EPSF 1e-5f

typedef __bf16 bf16x8 __attribute__((ext_vector_type(8)));
typedef __bf16 bf16x4 __attribute__((ext_vector_type(4)));
typedef float  f32x4  __attribute__((ext_vector_type(4)));

// ---------------- K0: weight prep (fp32 -> bf16, de-interleave k/v rows), zero kv accum ----
__global__ void k0_prep(const float* __restrict__ Wqkv, const float* __restrict__ Wproj,
                        __bf16* __restrict__ Wkv, __bf16* __restrict__ Wp,
                        float* __restrict__ kv) {
  int idx = blockIdx.x * 256 + threadIdx.x;   // grid 512*256 = 131072
  if (idx < 32768) kv[idx] = 0.f;             // kv accumulator [8][16][16][16]
  {
    int r = idx >> 8, c = idx & 255;
    int half = r >> 8;          // 0:k 1:v
    int rr = r & 255;
    int h = rr >> 4, d = rr & 15;
    Wkv[idx] = (__bf16)Wqkv[(h*48 + 16 + half*16 + d)*256 + c];
  }
  if (idx < 65536) Wp[idx] = (__bf16)Wproj[idx];
}

// ---------------- K1a: k,v GEMM (swapped operands) + lane-local LN -> kvT[b][c][HW] bf16 ----
// Grid 2048 (one 64-row tile per block), 8 waves. Two column passes (256 cols each):
// wave w covers cols p*256 + w*32 .. +31. acc[2][4] = 32 VGPRs (no spill).
// Per-wave private LDS transpose buffer -> only ONE barrier per block.
__launch_bounds__(512)
__global__ void k1a(const float* __restrict__ x, const __bf16* __restrict__ Wkv,
                    const float* __restrict__ bqkv,
                    const float* __restrict__ klnw, const float* __restrict__ klnb,
                    const float* __restrict__ vlnw, const float* __restrict__ vlnb,
                    __bf16* __restrict__ kvT) {
  __shared__ __align__(16) char smem[33792 + 8*4608];   // xs[64][264] + 8 * tT[32][72]
  __bf16 (*xs)[264] = reinterpret_cast<__bf16(*)[264]>(smem);
  const int tid = threadIdx.x;
  const int w = tid >> 6, l = tid & 63, lr = l & 15, g = l >> 4;
  __bf16 (*tT)[72] = reinterpret_cast<__bf16(*)[72]>(smem + 33792 + w*4608);  // [32][72]

  const long row0 = (long)blockIdx.x * 64;
  const int b    = (int)(row0 >> 14);
  const int rloc = (int)(row0 & 16383);

  // stage x tile -> bf16 LDS (coalesced 1KB per wave-instruction)
  #pragma unroll
  for (int i = 0; i < 8; ++i) {
    int idx = tid + i*512;
    int r = idx >> 6, c4 = (idx & 63) << 2;
    f32x4 v = *reinterpret_cast<const f32x4*>(x + (row0 + r)*256 + c4);
    bf16x4 pk; pk[0]=(__bf16)v[0]; pk[1]=(__bf16)v[1]; pk[2]=(__bf16)v[2]; pk[3]=(__bf16)v[3];
    *reinterpret_cast<bf16x4*>(&xs[r][c4]) = pk;
  }
  __syncthreads();   // the only barrier

  const int qh = l >> 3, seg = l & 7;

  #pragma unroll
  for (int p = 0; p < 2; ++p) {
    const int cbase = p*256 + w*32;

    f32x4 acc[2][4];
    for (int cb=0;cb<2;cb++)
      for (int rb=0;rb<4;rb++)
        for (int j=0;j<4;j++) acc[cb][rb][j]=0.f;

    #pragma unroll
    for (int kc = 0; kc < 8; ++kc) {
      const int kb = kc*32 + g*8;
      bf16x8 af[2], bf_[4];
      #pragma unroll
      for (int cb=0;cb<2;cb++)
        af[cb] = *reinterpret_cast<const bf16x8*>(Wkv + (size_t)(cbase + cb*16 + lr)*256 + kb);
      #pragma unroll
      for (int rb=0;rb<4;rb++)
        bf_[rb] = *reinterpret_cast<const bf16x8*>(&xs[rb*16+lr][kb]);
      #pragma unroll
      for (int cb=0;cb<2;cb++) {
        #pragma unroll
        for (int rb=0;rb<4;rb++)
          acc[cb][rb] = __builtin_amdgcn_mfma_f32_16x16x32_bf16(af[cb], bf_[rb], acc[cb][rb], 0,0,0);
      }
    }

    // LN per 16-col head group (d = 4g+j lane-local; reduce = 3 adds + 2 shfls),
    // transposed store into per-wave tT[c-within-32][r]
    #pragma unroll
    for (int cb=0;cb<2;cb++) {
      const int c0 = cbase + cb*16;
      const int isv = c0 >> 8, h = (c0 & 255) >> 4;
      const f32x4 bb  = *reinterpret_cast<const f32x4*>(bqkv + h*48 + 16 + isv*16 + 4*g);
      const f32x4 lwv = *reinterpret_cast<const f32x4*>((isv ? vlnw : klnw) + h*16 + 4*g);
      const f32x4 lbv = *reinterpret_cast<const f32x4*>((isv ? vlnb : klnb) + h*16 + 4*g);
      #pragma unroll
      for (int rb=0;rb<4;rb++) {
        float v0 = acc[cb][rb][0] + bb[0];
        float v1 = acc[cb][rb][1] + bb[1];
        float v2 = acc[cb][rb][2] + bb[2];
        float v3 = acc[cb][rb][3] + bb[3];
        float sum = v0+v1+v2+v3;
        sum += __shfl_xor(sum, 16); sum += __shfl_xor(sum, 32);
        const float mu = sum * 0.0625f;
        const float d0=v0-mu, d1=v1-mu, d2=v2-mu, d3=v3-mu;
        float q = d0*d0 + d1*d1 + d2*d2 + d3*d3;
        q += __shfl_xor(q, 16); q += __shfl_xor(q, 32);
        const float sc = 1.f/(sqrtf(q*(1.f/15.f)) + EPSF);   // ddof=1, /(std+eps)
        const int rr = rb*16 + lr;
        tT[cb*16 + 4*g+0][rr] = (__bf16)(lwv[0]*d0*sc + lbv[0]);
        tT[cb*16 + 4*g+1][rr] = (__bf16)(lwv[1]*d1*sc + lbv[1]);
        tT[cb*16 + 4*g+2][rr] = (__bf16)(lwv[2]*d2*sc + lbv[2]);
        tT[cb*16 + 4*g+3][rr] = (__bf16)(lwv[3]*d3*sc + lbv[3]);
      }
    }

    // stream out: kvT[(b*512 + cbase + q)][rloc .. rloc+63], 128B coalesced per q-row
    #pragma unroll
    for (int qo = 0; qo < 4; ++qo) {
      const int q = qo*8 + qh;
      bf16x8 vv = *reinterpret_cast<const bf16x8*>(&tT[q][seg*8]);
      *reinterpret_cast<bf16x8*>(kvT + ((size_t)b*512 + cbase + q)*16384 + rloc + seg*8) = vv;
    }
  }
}

// ---------------- K1b: kv[b][h][d][e] = sum_r k'[d][r] v'[r][e] (streaming MFMA) ----------
// kvT rows 0..255 = k' (h*16+d), 256..511 = v' (h*16+e), each [16384] bf16.
// Grid 2048 = (b,h)*16 r-splits; block 256 thr (4 waves), wave covers 256 rows = 8 MFMA.
__launch_bounds__(256)
__global__ void k1b(const __bf16* __restrict__ kvT, float* __restrict__ kvout) {
  const int tid = threadIdx.x;
  const int wv = tid >> 6, l = tid & 63, lr = l & 15, g = l >> 4;
  const int bh = blockIdx.x >> 4, rs = blockIdx.x & 15;
  const int b = bh >> 4, h = bh & 15;
  const int r0 = rs*1024 + wv*256;

  const __bf16* pa = kvT + ((size_t)(b*512 +       h*16 + lr))*16384;  // k'[d=lr][*]
  const __bf16* pb = kvT + ((size_t)(b*512 + 256 + h*16 + lr))*16384;  // v'[e=lr][*]

  f32x4 acc; acc[0]=0.f; acc[1]=0.f; acc[2]=0.f; acc[3]=0.f;
  #pragma unroll
  for (int it = 0; it < 8; ++it) {
    const int r = r0 + it*32 + g*8;
    bf16x8 a  = *reinterpret_cast<const bf16x8*>(pa + r);   // A[d=lr][k=r..r+7]
    bf16x8 bv = *reinterpret_cast<const bf16x8*>(pb + r);   // B[k=r..r+7][e=lr]
    acc = __builtin_amdgcn_mfma_f32_16x16x32_bf16(a, bv, acc, 0,0,0);
  }
  float* dst = kvout + (size_t)bh*256;
  #pragma unroll
  for (int j=0;j<4;j++)
    atomicAdd(dst + (g*4+j)*16 + lr, acc[j]);   // kv[d=4g+j][e=lr]
}

// ---------------- K2: Wq_eff[b][h*16+e][c] = sum_d kv[b,h,d,e]/HW * Wq[h*48+d][c] ----------
__global__ void k2_weff(const float* __restrict__ Wqkv, const float* __restrict__ bqkv,
                        const float* __restrict__ kvin,
                        __bf16* __restrict__ Wqe, float* __restrict__ beff) {
  const int b = blockIdx.x >> 4, h = blockIdx.x & 15;
  const int c = threadIdx.x;
  __shared__ float kvs[16][16]; // [d][e]
  kvs[c >> 4][c & 15] = kvin[(b*16 + h)*256 + c] * (1.f/16384.f);
  __syncthreads();
  #pragma unroll 4
  for (int e=0;e<16;e++) {
    float acc = 0.f;
    #pragma unroll
    for (int d=0; d<16; d++)
      acc += kvs[d][e] * Wqkv[(h*48 + d)*256 + c];
    Wqe[((size_t)b*256 + h*16 + e)*256 + c] = (__bf16)acc;
  }
  if (c < 16) {
    float acc = 0.f;
    #pragma unroll
    for (int d=0; d<16; d++) acc += kvs[d][c] * bqkv[h*48 + d];
    beff[b*256 + h*16 + c] = acc;
  }
}

// ---------------- K3: fused o = x@Wq_eff^T; ret = o+beff+x; proj = ret@Wp^T; y=gelu+x ----
__launch_bounds__(512, 4)
__global__ void k3_fused(const float* __restrict__ x, const __bf16* __restrict__ Wqe,
                         const float* __restrict__ beff, const __bf16* __restrict__ Wp,
                         const float* __restrict__ bproj, float* __restrict__ out) {
  __shared__ __align__(16) __bf16 xs[64][264];
  __shared__ __align__(16) __bf16 rs[64][264];
  const int tid = threadIdx.x;
  const long browg = (long)blockIdx.x * 64;
  const int b = (int)(browg >> 14);
  const int w = tid>>6, l = tid&63, lr = l&15, g = l>>4;

  #pragma unroll
  for (int i = 0; i < 8; ++i) {
    int idx = tid + i*512;
    int r = idx >> 6, c4 = (idx & 63) << 2;
    f32x4 v = *reinterpret_cast<const f32x4*>(x + (browg + r)*256 + c4);
    bf16x4 pk; pk[0]=(__bf16)v[0]; pk[1]=(__bf16)v[1]; pk[2]=(__bf16)v[2]; pk[3]=(__bf16)v[3];
    *reinterpret_cast<bf16x4*>(&xs[r][c4]) = pk;
  }
  __syncthreads();

  const __bf16* Bq = Wqe + (size_t)b*65536;

  f32x4 acc[2][4];
  for (int cb=0;cb<2;cb++)
    for (int rb=0;rb<4;rb++)
      for (int j=0;j<4;j++) acc[cb][rb][j]=0.f;
  #pragma unroll
  for (int kc=0;kc<8;kc++) {
    const int kb = kc*32 + g*8;
    bf16x8 af[2], bf_[4];
    #pragma unroll
    for (int cb=0;cb<2;cb++)
      af[cb] = *reinterpret_cast<const bf16x8*>(Bq + (size_t)(w*32 + cb*16 + lr)*256 + kb);
    #pragma unroll
    for (int rb=0;rb<4;rb++)
      bf_[rb] = *reinterpret_cast<const bf16x8*>(&xs[rb*16+lr][kb]);
    #pragma unroll
    for (int cb=0;cb<2;cb++) {
      #pragma unroll
      for (int rb=0;rb<4;rb++)
        acc[cb][rb] = __builtin_amdgcn_mfma_f32_16x16x32_bf16(af[cb], bf_[rb], acc[cb][rb], 0,0,0);
    }
  }

  #pragma unroll
  for (int cb=0;cb<2;cb++) {
    const int c0 = w*32 + cb*16 + 4*g;
    const f32x4 be = *reinterpret_cast<const f32x4*>(beff + b*256 + c0);
    #pragma unroll
    for (int rb=0;rb<4;rb++) {
      const int r = rb*16 + lr;
      bf16x4 xv = *reinterpret_cast<const bf16x4*>(&xs[r][c0]);
      bf16x4 pk;
      #pragma unroll
      for (int j=0;j<4;j++)
        pk[j] = (__bf16)(acc[cb][rb][j] + be[j] + (float)xv[j]);
      *reinterpret_cast<bf16x4*>(&rs[r][c0]) = pk;
    }
  }
  __syncthreads();

  f32x4 acc2[2][4];
  for (int cb=0;cb<2;cb++)
    for (int rb=0;rb<4;rb++)
      for (int j=0;j<4;j++) acc2[cb][rb][j]=0.f;
  #pragma unroll
  for (int kc=0;kc<8;kc++) {
    const int kb = kc*32 + g*8;
    bf16x8 af[2], bf_[4];
    #pragma unroll
    for (int cb=0;cb<2;cb++)
      af[cb] = *reinterpret_cast<const bf16x8*>(Wp + (size_t)(w*32 + cb*16 + lr)*256 + kb);
    #pragma unroll
    for (int rb=0;rb<4;rb++)
      bf_[rb] = *reinterpret_cast<const bf16x8*>(&rs[rb*16+lr][kb]);
    #pragma unroll
    for (int cb=0;cb<2;cb++) {
      #pragma unroll
      for (int rb=0;rb<4;rb++)
        acc2[cb][rb] = __builtin_amdgcn_mfma_f32_16x16x32_bf16(af[cb], bf_[rb], acc2[cb][rb], 0,0,0);
    }
  }

  #pragma unroll
  for (int cb=0;cb<2;cb++) {
    const int c0 = w*32 + cb*16 + 4*g;
    const f32x4 bp4 = *reinterpret_cast<const f32x4*>(bproj + c0);
    #pragma unroll
    for (int rb=0;rb<4;rb++) {
      const long gr = browg + rb*16 + lr;
      const f32x4 xv = *reinterpret_cast<const f32x4*>(x + gr*256 + c0);
      f32x4 o;
      #pragma unroll
      for (int j=0;j<4;j++) {
        float z = acc2[cb][rb][j] + bp4[j];
        o[j] = 0.5f*z*(1.f + erff(z*0.70710678118f)) + xv[j];
      }
      *reinterpret_cast<f32x4*>(out + gr*256 + c0) = o;
    }
  }
}

extern "C" void kernel_launch(void* const* d_in, const int* in_sizes, int n_in,
                              void* d_out, int out_size, void* d_ws, size_t ws_size,
                              hipStream_t stream) {
  const float* x    = (const float*)d_in[0];
  const float* Wqkv = (const float*)d_in[1];
  const float* bqkv = (const float*)d_in[2];
  const float* klnw = (const float*)d_in[3];
  const float* klnb = (const float*)d_in[4];
  const float* vlnw = (const float*)d_in[5];
  const float* vlnb = (const float*)d_in[6];
  const float* Wproj= (const float*)d_in[7];
  const float* bproj= (const float*)d_in[8];
  float* out = (float*)d_out;

  char* ws = (char*)d_ws;
  __bf16* Wkv = (__bf16*)(ws);                 // 512*256*2   = 262144
  __bf16* Wp  = (__bf16*)(ws + 262144);        // 256*256*2   = 131072
  float*  kv  = (float*) (ws + 393216);        // 32768*4     = 131072
  __bf16* Wqe = (__bf16*)(ws + 524288);        // 8*256*256*2 = 1048576
  float*  beff= (float*) (ws + 1572864);       // 8*256*4     = 8192

  // d_out doubles as the 134 MB k'/v' scratch (exact size match: 8*512*16384*2 B);
  // K3 fully overwrites it with the final output afterwards.
  __bf16* kvT = (__bf16*)d_out;

  k0_prep <<<512, 256, 0, stream>>>(Wqkv, Wproj, Wkv, Wp, kv);
  k1a     <<<2048, 512, 0, stream>>>(x, Wkv, bqkv, klnw, klnb, vlnw, vlnb, kvT);
  k1b     <<<2048, 256, 0, stream>>>(kvT, kv);
  k2_weff <<<128, 256, 0, stream>>>(Wqkv, bqkv, kv, Wqe, beff);
  k3_fused<<<2048, 512, 0, stream>>>(x, Wqe, beff, Wp, bproj, out);
}

// Round 5
// 212.832 us; speedup vs baseline: 1.6893x; 1.1815x over previous
//
#include <hip/hip_runtime.h>
#include <hip/hip_bf16.h>
#include <math.h>

// qkv_attn: x[8,16384,256] fp32. kv = LN(k)^T LN(v)/HW folded into Wq (per batch).
// R5: k1b folded into k1a (wave w owns heads {2w,2w+1} for BOTH k (pass0) and v (pass1)
// -> kv MFMAs run on private LDS tiles; no global k'/v' round-trip). 16-deep explicit
// weight preloads in k1a and k3 to fix the serial L2-load latency chain (VGPR was 52).

#define EPSF 1e-5f

typedef __bf16 bf16x8 __attribute__((ext_vector_type(8)));
typedef __bf16 bf16x4 __attribute__((ext_vector_type(4)));
typedef float  f32x4  __attribute__((ext_vector_type(4)));

// ---------------- K0: weight prep (fp32 -> bf16, de-interleave k/v rows), zero kv accum ----
__global__ void k0_prep(const float* __restrict__ Wqkv, const float* __restrict__ Wproj,
                        __bf16* __restrict__ Wkv, __bf16* __restrict__ Wp,
                        float* __restrict__ kv) {
  int idx = blockIdx.x * 256 + threadIdx.x;   // grid 512*256 = 131072
  if (idx < 32768) kv[idx] = 0.f;             // kv accumulator [8][16][16][16]
  {
    int r = idx >> 8, c = idx & 255;
    int half = r >> 8;          // 0:k 1:v
    int rr = r & 255;
    int h = rr >> 4, d = rr & 15;
    Wkv[idx] = (__bf16)Wqkv[(h*48 + 16 + half*16 + d)*256 + c];
  }
  if (idx < 65536) Wp[idx] = (__bf16)Wproj[idx];
}

// ---------------- K1a: k,v GEMM + LN + local kv reduction ----------------
// Grid 2048 (one 64-row tile/block), 8 waves. Pass 0: k-cols w*32..+31 (heads 2w,2w+1);
// pass 1: v-cols 256+w*32..+31 (same heads). After both passes the wave holds k',v' of
// its 2 heads in private LDS -> 4 kv MFMAs + 8 atomics. tT_v overlays dead xs region.
__launch_bounds__(512, 4)
__global__ void k1a(const float* __restrict__ x, const __bf16* __restrict__ Wkv,
                    const float* __restrict__ bqkv,
                    const float* __restrict__ klnw, const float* __restrict__ klnb,
                    const float* __restrict__ vlnw, const float* __restrict__ vlnb,
                    float* __restrict__ kvout) {
  __shared__ __align__(16) char smem[70656];   // xs[64][264] (33792) | tTk 8x[32][72] (36864)
  __bf16 (*xs)[264] = reinterpret_cast<__bf16(*)[264]>(smem);
  const int tid = threadIdx.x;
  const int w = tid >> 6, l = tid & 63, lr = l & 15, g = l >> 4;
  __bf16 (*tTk)[72] = reinterpret_cast<__bf16(*)[72]>(smem + 33792 + w*4608); // [c 32][r 72]
  __bf16 (*tTv)[64] = reinterpret_cast<__bf16(*)[64]>(smem + w*4096);         // [c 32][r 64] swz

  const long row0 = (long)blockIdx.x * 64;
  const int b = (int)(row0 >> 14);

  // stage x tile -> bf16 LDS
  #pragma unroll
  for (int i = 0; i < 8; ++i) {
    int idx = tid + i*512;
    int r = idx >> 6, c4 = (idx & 63) << 2;
    f32x4 v = *reinterpret_cast<const f32x4*>(x + (row0 + r)*256 + c4);
    bf16x4 pk; pk[0]=(__bf16)v[0]; pk[1]=(__bf16)v[1]; pk[2]=(__bf16)v[2]; pk[3]=(__bf16)v[3];
    *reinterpret_cast<bf16x4*>(&xs[r][c4]) = pk;
  }

  // preload ALL pass-0 (k) weight fragments: 16 independent L2 loads in flight
  bf16x8 wk[2][8];
  #pragma unroll
  for (int cb=0;cb<2;cb++) {
    const __bf16* wp = Wkv + (size_t)(w*32 + cb*16 + lr)*256 + g*8;
    #pragma unroll
    for (int kc=0;kc<8;kc++) wk[cb][kc] = *reinterpret_cast<const bf16x8*>(wp + kc*32);
  }
  __syncthreads();

  // ---- pass 0 (k) GEMM ----
  f32x4 acc[2][4];
  for (int cb=0;cb<2;cb++) for (int rb=0;rb<4;rb++)
    for (int j=0;j<4;j++) acc[cb][rb][j]=0.f;
  #pragma unroll
  for (int kc = 0; kc < 8; ++kc) {
    const int kb = kc*32 + g*8;
    bf16x8 bf_[4];
    #pragma unroll
    for (int rb=0;rb<4;rb++)
      bf_[rb] = *reinterpret_cast<const bf16x8*>(&xs[rb*16+lr][kb]);
    #pragma unroll
    for (int cb=0;cb<2;cb++)
      #pragma unroll
      for (int rb=0;rb<4;rb++)
        acc[cb][rb] = __builtin_amdgcn_mfma_f32_16x16x32_bf16(wk[cb][kc], bf_[rb], acc[cb][rb], 0,0,0);
  }

  // preload pass-1 (v) weights while LN runs
  bf16x8 wv[2][8];
  #pragma unroll
  for (int cb=0;cb<2;cb++) {
    const __bf16* wp = Wkv + (size_t)(256 + w*32 + cb*16 + lr)*256 + g*8;
    #pragma unroll
    for (int kc=0;kc<8;kc++) wv[cb][kc] = *reinterpret_cast<const bf16x8*>(wp + kc*32);
  }

  // ---- pass 0 LN -> tTk (private, no barrier needed) ----
  #pragma unroll
  for (int cb=0;cb<2;cb++) {
    const int h = 2*w + cb;
    const f32x4 bb  = *reinterpret_cast<const f32x4*>(bqkv + h*48 + 16 + 4*g);
    const f32x4 lwv = *reinterpret_cast<const f32x4*>(klnw + h*16 + 4*g);
    const f32x4 lbv = *reinterpret_cast<const f32x4*>(klnb + h*16 + 4*g);
    #pragma unroll
    for (int rb=0;rb<4;rb++) {
      float v0 = acc[cb][rb][0] + bb[0];
      float v1 = acc[cb][rb][1] + bb[1];
      float v2 = acc[cb][rb][2] + bb[2];
      float v3 = acc[cb][rb][3] + bb[3];
      float sum = v0+v1+v2+v3;
      sum += __shfl_xor(sum, 16); sum += __shfl_xor(sum, 32);
      const float mu = sum * 0.0625f;
      const float d0=v0-mu, d1=v1-mu, d2=v2-mu, d3=v3-mu;
      float q = d0*d0 + d1*d1 + d2*d2 + d3*d3;
      q += __shfl_xor(q, 16); q += __shfl_xor(q, 32);
      const float sc = 1.f/(sqrtf(q*(1.f/15.f)) + EPSF);
      const int rr = rb*16 + lr;
      tTk[cb*16 + 4*g+0][rr] = (__bf16)(lwv[0]*d0*sc + lbv[0]);
      tTk[cb*16 + 4*g+1][rr] = (__bf16)(lwv[1]*d1*sc + lbv[1]);
      tTk[cb*16 + 4*g+2][rr] = (__bf16)(lwv[2]*d2*sc + lbv[2]);
      tTk[cb*16 + 4*g+3][rr] = (__bf16)(lwv[3]*d3*sc + lbv[3]);
    }
  }

  // ---- pass 1 (v) GEMM ----
  for (int cb=0;cb<2;cb++) for (int rb=0;rb<4;rb++)
    for (int j=0;j<4;j++) acc[cb][rb][j]=0.f;
  #pragma unroll
  for (int kc = 0; kc < 8; ++kc) {
    const int kb = kc*32 + g*8;
    bf16x8 bf_[4];
    #pragma unroll
    for (int rb=0;rb<4;rb++)
      bf_[rb] = *reinterpret_cast<const bf16x8*>(&xs[rb*16+lr][kb]);
    #pragma unroll
    for (int cb=0;cb<2;cb++)
      #pragma unroll
      for (int rb=0;rb<4;rb++)
        acc[cb][rb] = __builtin_amdgcn_mfma_f32_16x16x32_bf16(wv[cb][kc], bf_[rb], acc[cb][rb], 0,0,0);
  }
  __syncthreads();   // ALL waves done reading xs; its space becomes tTv

  // ---- pass 1 LN -> tTv (XOR-swizzled rows: idx ^ ((c&7)<<3)) ----
  #pragma unroll
  for (int cb=0;cb<2;cb++) {
    const int h = 2*w + cb;
    const f32x4 bb  = *reinterpret_cast<const f32x4*>(bqkv + h*48 + 32 + 4*g);
    const f32x4 lwv = *reinterpret_cast<const f32x4*>(vlnw + h*16 + 4*g);
    const f32x4 lbv = *reinterpret_cast<const f32x4*>(vlnb + h*16 + 4*g);
    #pragma unroll
    for (int rb=0;rb<4;rb++) {
      float v0 = acc[cb][rb][0] + bb[0];
      float v1 = acc[cb][rb][1] + bb[1];
      float v2 = acc[cb][rb][2] + bb[2];
      float v3 = acc[cb][rb][3] + bb[3];
      float sum = v0+v1+v2+v3;
      sum += __shfl_xor(sum, 16); sum += __shfl_xor(sum, 32);
      const float mu = sum * 0.0625f;
      const float d0=v0-mu, d1=v1-mu, d2=v2-mu, d3=v3-mu;
      float q = d0*d0 + d1*d1 + d2*d2 + d3*d3;
      q += __shfl_xor(q, 16); q += __shfl_xor(q, 32);
      const float sc = 1.f/(sqrtf(q*(1.f/15.f)) + EPSF);
      const int rr = rb*16 + lr;
      tTv[cb*16 + 4*g+0][rr ^ (((4*g+0)&7)<<3)] = (__bf16)(lwv[0]*d0*sc + lbv[0]);
      tTv[cb*16 + 4*g+1][rr ^ (((4*g+1)&7)<<3)] = (__bf16)(lwv[1]*d1*sc + lbv[1]);
      tTv[cb*16 + 4*g+2][rr ^ (((4*g+2)&7)<<3)] = (__bf16)(lwv[2]*d2*sc + lbv[2]);
      tTv[cb*16 + 4*g+3][rr ^ (((4*g+3)&7)<<3)] = (__bf16)(lwv[3]*d3*sc + lbv[3]);
    }
  }

  // ---- kv_h += k'^T v' (private LDS, no barrier: per-wave tiles) ----
  #pragma unroll
  for (int hh=0; hh<2; ++hh) {
    f32x4 c; c[0]=0.f; c[1]=0.f; c[2]=0.f; c[3]=0.f;
    #pragma unroll
    for (int ch=0; ch<2; ++ch) {
      const int s = ch*32 + g*8;
      bf16x8 a  = *reinterpret_cast<const bf16x8*>(&tTk[hh*16 + lr][s]);
      bf16x8 bv = *reinterpret_cast<const bf16x8*>(&tTv[hh*16 + lr][s ^ ((lr&7)<<3)]);
      c = __builtin_amdgcn_mfma_f32_16x16x32_bf16(a, bv, c, 0,0,0);
    }
    float* dst = kvout + ((size_t)(b*16 + 2*w + hh) << 8);
    #pragma unroll
    for (int j=0;j<4;j++)
      atomicAdd(dst + (4*g+j)*16 + lr, c[j]);   // kv[d=4g+j][e=lr]
  }
}

// ---------------- K2: Wq_eff[b][h*16+e][c] = sum_d kv[b,h,d,e]/HW * Wq[h*48+d][c] ----------
__global__ void k2_weff(const float* __restrict__ Wqkv, const float* __restrict__ bqkv,
                        const float* __restrict__ kvin,
                        __bf16* __restrict__ Wqe, float* __restrict__ beff) {
  const int b = blockIdx.x >> 4, h = blockIdx.x & 15;
  const int c = threadIdx.x;
  __shared__ float kvs[16][16]; // [d][e]
  kvs[c >> 4][c & 15] = kvin[(b*16 + h)*256 + c] * (1.f/16384.f);
  __syncthreads();
  #pragma unroll 4
  for (int e=0;e<16;e++) {
    float acc = 0.f;
    #pragma unroll
    for (int d=0; d<16; d++)
      acc += kvs[d][e] * Wqkv[(h*48 + d)*256 + c];
    Wqe[((size_t)b*256 + h*16 + e)*256 + c] = (__bf16)acc;
  }
  if (c < 16) {
    float acc = 0.f;
    #pragma unroll
    for (int d=0; d<16; d++) acc += kvs[d][c] * bqkv[h*48 + d];
    beff[b*256 + h*16 + c] = acc;
  }
}

// ---------------- K3: fused o = x@Wq_eff^T; ret = o+beff+x; proj = ret@Wp^T; y=gelu+x ----
__launch_bounds__(512, 4)
__global__ void k3_fused(const float* __restrict__ x, const __bf16* __restrict__ Wqe,
                         const float* __restrict__ beff, const __bf16* __restrict__ Wp,
                         const float* __restrict__ bproj, float* __restrict__ out) {
  __shared__ __align__(16) __bf16 xs[64][264];
  __shared__ __align__(16) __bf16 rs[64][264];
  const int tid = threadIdx.x;
  const long browg = (long)blockIdx.x * 64;
  const int b = (int)(browg >> 14);
  const int w = tid>>6, l = tid&63, lr = l&15, g = l>>4;

  #pragma unroll
  for (int i = 0; i < 8; ++i) {
    int idx = tid + i*512;
    int r = idx >> 6, c4 = (idx & 63) << 2;
    f32x4 v = *reinterpret_cast<const f32x4*>(x + (browg + r)*256 + c4);
    bf16x4 pk; pk[0]=(__bf16)v[0]; pk[1]=(__bf16)v[1]; pk[2]=(__bf16)v[2]; pk[3]=(__bf16)v[3];
    *reinterpret_cast<bf16x4*>(&xs[r][c4]) = pk;
  }

  // preload GEMM1 weights (Wq_eff, L2-resident) during staging
  const __bf16* Bq = Wqe + (size_t)b*65536;
  bf16x8 wq[2][8];
  #pragma unroll
  for (int cb=0;cb<2;cb++) {
    const __bf16* wp = Bq + (size_t)(w*32 + cb*16 + lr)*256 + g*8;
    #pragma unroll
    for (int kc=0;kc<8;kc++) wq[cb][kc] = *reinterpret_cast<const bf16x8*>(wp + kc*32);
  }
  __syncthreads();

  f32x4 acc[2][4];
  for (int cb=0;cb<2;cb++) for (int rb=0;rb<4;rb++)
    for (int j=0;j<4;j++) acc[cb][rb][j]=0.f;
  #pragma unroll
  for (int kc=0;kc<8;kc++) {
    const int kb = kc*32 + g*8;
    bf16x8 bf_[4];
    #pragma unroll
    for (int rb=0;rb<4;rb++)
      bf_[rb] = *reinterpret_cast<const bf16x8*>(&xs[rb*16+lr][kb]);
    #pragma unroll
    for (int cb=0;cb<2;cb++)
      #pragma unroll
      for (int rb=0;rb<4;rb++)
        acc[cb][rb] = __builtin_amdgcn_mfma_f32_16x16x32_bf16(wq[cb][kc], bf_[rb], acc[cb][rb], 0,0,0);
  }

  // preload GEMM2 weights while ret-phase runs
  bf16x8 wpj[2][8];
  #pragma unroll
  for (int cb=0;cb<2;cb++) {
    const __bf16* wp = Wp + (size_t)(w*32 + cb*16 + lr)*256 + g*8;
    #pragma unroll
    for (int kc=0;kc<8;kc++) wpj[cb][kc] = *reinterpret_cast<const bf16x8*>(wp + kc*32);
  }

  // ret = o + beff + x -> rs
  #pragma unroll
  for (int cb=0;cb<2;cb++) {
    const int c0 = w*32 + cb*16 + 4*g;
    const f32x4 be = *reinterpret_cast<const f32x4*>(beff + b*256 + c0);
    #pragma unroll
    for (int rb=0;rb<4;rb++) {
      const int r = rb*16 + lr;
      bf16x4 xv = *reinterpret_cast<const bf16x4*>(&xs[r][c0]);
      bf16x4 pk;
      #pragma unroll
      for (int j=0;j<4;j++)
        pk[j] = (__bf16)(acc[cb][rb][j] + be[j] + (float)xv[j]);
      *reinterpret_cast<bf16x4*>(&rs[r][c0]) = pk;
    }
  }
  __syncthreads();

  f32x4 acc2[2][4];
  for (int cb=0;cb<2;cb++) for (int rb=0;rb<4;rb++)
    for (int j=0;j<4;j++) acc2[cb][rb][j]=0.f;
  #pragma unroll
  for (int kc=0;kc<8;kc++) {
    const int kb = kc*32 + g*8;
    bf16x8 bf_[4];
    #pragma unroll
    for (int rb=0;rb<4;rb++)
      bf_[rb] = *reinterpret_cast<const bf16x8*>(&rs[rb*16+lr][kb]);
    #pragma unroll
    for (int cb=0;cb<2;cb++)
      #pragma unroll
      for (int rb=0;rb<4;rb++)
        acc2[cb][rb] = __builtin_amdgcn_mfma_f32_16x16x32_bf16(wpj[cb][kc], bf_[rb], acc2[cb][rb], 0,0,0);
  }

  #pragma unroll
  for (int cb=0;cb<2;cb++) {
    const int c0 = w*32 + cb*16 + 4*g;
    const f32x4 bp4 = *reinterpret_cast<const f32x4*>(bproj + c0);
    #pragma unroll
    for (int rb=0;rb<4;rb++) {
      const long gr = browg + rb*16 + lr;
      const f32x4 xv = *reinterpret_cast<const f32x4*>(x + gr*256 + c0);
      f32x4 o;
      #pragma unroll
      for (int j=0;j<4;j++) {
        float z = acc2[cb][rb][j] + bp4[j];
        o[j] = 0.5f*z*(1.f + erff(z*0.70710678118f)) + xv[j];
      }
      *reinterpret_cast<f32x4*>(out + gr*256 + c0) = o;
    }
  }
}

extern "C" void kernel_launch(void* const* d_in, const int* in_sizes, int n_in,
                              void* d_out, int out_size, void* d_ws, size_t ws_size,
                              hipStream_t stream) {
  const float* x    = (const float*)d_in[0];
  const float* Wqkv = (const float*)d_in[1];
  const float* bqkv = (const float*)d_in[2];
  const float* klnw = (const float*)d_in[3];
  const float* klnb = (const float*)d_in[4];
  const float* vlnw = (const float*)d_in[5];
  const float* vlnb = (const float*)d_in[6];
  const float* Wproj= (const float*)d_in[7];
  const float* bproj= (const float*)d_in[8];
  float* out = (float*)d_out;

  char* ws = (char*)d_ws;
  __bf16* Wkv = (__bf16*)(ws);                 // 512*256*2   = 262144
  __bf16* Wp  = (__bf16*)(ws + 262144);        // 256*256*2   = 131072
  float*  kv  = (float*) (ws + 393216);        // 32768*4     = 131072
  __bf16* Wqe = (__bf16*)(ws + 524288);        // 8*256*256*2 = 1048576
  float*  beff= (float*) (ws + 1572864);       // 8*256*4     = 8192

  k0_prep <<<512, 256, 0, stream>>>(Wqkv, Wproj, Wkv, Wp, kv);
  k1a     <<<2048, 512, 0, stream>>>(x, Wkv, bqkv, klnw, klnb, vlnw, vlnb, kv);
  k2_weff <<<128, 256, 0, stream>>>(Wqkv, bqkv, kv, Wqe, beff);
  k3_fused<<<2048, 512, 0, stream>>>(x, Wqe, beff, Wp, bproj, out);
}